// Round 12
// baseline (375.394 us; speedup 1.0000x reference)
//
#include <hip/hip_runtime.h>

#define NN 100000
#define NNPAD 100352   // 196*512
#define NE 1600000
#define NG 64
#define DI 128
#define DH 256
#define DO 128
#define SEG 32768      // cmT s-segment per block (128 KB LDS)

using short8 = __attribute__((ext_vector_type(8))) short;
using f32x4  = __attribute__((ext_vector_type(4))) float;

__device__ __forceinline__ float bf2f(unsigned short u) {
    return __uint_as_float(((unsigned)u) << 16);
}
__device__ __forceinline__ unsigned short f2bf(float f) {
    unsigned u = __float_as_uint(f);
    unsigned r = (u + 0x7FFFu + ((u >> 16) & 1u)) >> 16;   // RNE
    return (unsigned short)r;
}

// ---------------- prep: x -> bf16, W1 -> w1t, dst histogram (merged) ----------------
__global__ void k_prep(const float* __restrict__ x, unsigned short* __restrict__ xbf,
                       const float* __restrict__ W1, unsigned short* __restrict__ w1t,
                       const int* __restrict__ dst, int* __restrict__ cnt) {
    int i = blockIdx.x * blockDim.x + threadIdx.x;
    const int NX4 = NN * 32;
    if (i < NX4) {
        float4 v = ((const float4*)x)[i];
        ushort4 o;
        o.x = f2bf(v.x); o.y = f2bf(v.y); o.z = f2bf(v.z); o.w = f2bf(v.w);
        ((ushort4*)xbf)[i] = o;
    } else if (i < NX4 + DI * DH) {
        int t = i - NX4;
        int k = t / DH, n = t % DH;
        w1t[n * DI + k] = f2bf(W1[t]);
    }
    if (i < NE) atomicAdd(&cnt[dst[i]], 1);
}

// ---------------- exclusive scan (2-level) ----------------

__global__ void k_scan1(const int* __restrict__ in, int* __restrict__ out,
                        int* __restrict__ bsum, int n) {
    __shared__ int sh[256];
    int t = threadIdx.x;
    int i = blockIdx.x * 256 + t;
    int v = (i < n) ? in[i] : 0;
    sh[t] = v;
    __syncthreads();
    for (int off = 1; off < 256; off <<= 1) {
        int add = (t >= off) ? sh[t - off] : 0;
        __syncthreads();
        sh[t] += add;
        __syncthreads();
    }
    if (i < n) out[i] = sh[t] - v;
    if (t == 255) bsum[blockIdx.x] = sh[255];
}
__global__ void k_scan2(int* __restrict__ bsum, int* __restrict__ cntg, int nb) {
    __shared__ int sh[512];
    int t = threadIdx.x;
    if (t < NG) cntg[t] = 0;
    int v = (t < nb) ? bsum[t] : 0;
    sh[t] = v;
    __syncthreads();
    for (int off = 1; off < 512; off <<= 1) {
        int add = (t >= off) ? sh[t - off] : 0;
        __syncthreads();
        sh[t] += add;
        __syncthreads();
    }
    if (t < nb) bsum[t] = sh[t] - v;
}
// finalize rowst/cursor, dinv, gdv, per-graph counts
__global__ void k_scan3(int* __restrict__ rowst, const int* __restrict__ bsum,
                        int* __restrict__ cursor_deg, float* __restrict__ dinv,
                        const int* __restrict__ batch, int2* __restrict__ gdv,
                        int* __restrict__ cntg, int n, int total) {
    __shared__ int sh[NG];
    int t = threadIdx.x;
    if (t < NG) sh[t] = 0;
    __syncthreads();
    int i = blockIdx.x * 256 + t;
    if (i < n) {
        int deg = cursor_deg[i];
        float dv = rsqrtf((float)(deg + 1));
        dinv[i] = dv;
        int b = batch[i];
        int2 g; g.x = __float_as_int(dv); g.y = b;
        gdv[i] = g;
        atomicAdd(&sh[b], 1);
        int rv = rowst[i] + bsum[blockIdx.x];
        rowst[i] = rv;
        cursor_deg[i] = rv;   // becomes fill cursor
    }
    if (i == 0) rowst[n] = total;
    __syncthreads();
    if (t < NG && sh[t]) atomicAdd(&cntg[t], sh[t]);
}

// ---------------- CSR fill: dst-range passes ----------------

__global__ void k_fill_csr(const int* __restrict__ src, const int* __restrict__ dst,
                           int* __restrict__ cursor, int* __restrict__ csr_src,
                           int e, int lo, int hi) {
    int i = blockIdx.x * blockDim.x + threadIdx.x;
    if (i < e) {
        int d = dst[i];
        if (d >= lo && d < hi) {
            int pos = atomicAdd(&cursor[d], 1);
            csr_src[pos] = src[i];
        }
    }
}

// ---------------- cmT build from CSR: LDS-accumulated, coalesced stores ----------------
// Block (g, seg): accumulate cmT[g][slo..shi) in LDS over graph g's CSR rows
// (batch sorted -> contiguous dst range per graph), add self-loop diag, store.
__global__ __launch_bounds__(256) void k_cmbuild(const int* __restrict__ csr,
        const int* __restrict__ rowst, const float* __restrict__ dinv,
        const int2* __restrict__ gdv, const int* __restrict__ batch,
        float* __restrict__ cmT) {
    __shared__ float acc[SEG];          // 128 KB
    __shared__ int range[2];
    int g   = blockIdx.x >> 2;
    int seg = blockIdx.x & 3;
    int slo = seg * SEG;
    int shi = min(slo + SEG, NNPAD);
    int t = threadIdx.x;
    for (int i = t; i < SEG; i += 256) acc[i] = 0.f;
    if (t == 0) {          // lower_bound(batch, g), lower_bound(batch, g+1)
        int lo = 0, hi = NN;
        while (lo < hi) { int m = (lo + hi) >> 1; if (batch[m] < g) lo = m + 1; else hi = m; }
        range[0] = lo;
        int lo2 = lo, hi2 = NN;
        while (lo2 < hi2) { int m = (lo2 + hi2) >> 1; if (batch[m] < g + 1) lo2 = m + 1; else hi2 = m; }
        range[1] = lo2;
    }
    __syncthreads();
    int dstart = range[0], dend = range[1];
    for (int d = dstart + t; d < dend; d += 256) {
        float wd = dinv[d];
        int j0 = rowst[d], j1 = rowst[d + 1];
        for (int j = j0; j < j1; ++j) {
            int s = csr[j];
            if (s >= slo && s < shi)
                atomicAdd(&acc[s - slo], dinv[s] * wd);
        }
    }
    __syncthreads();
    float* row = cmT + (size_t)g * NNPAD;
    for (int i = t; i < shi - slo; i += 256) {
        int s = slo + i;
        float v = acc[i];
        if (s < NN) {
            int2 gv = gdv[s];
            if (gv.y == g) { float dv = __int_as_float(gv.x); v += dv * dv; }
        }
        row[s] = v;
    }
}

// ---------------- layer-1 aggregation (R5-proven) ----------------
__global__ __launch_bounds__(256) void k_agg16(const unsigned short* __restrict__ feat,
        const int* __restrict__ csr_src, const int* __restrict__ row_start,
        const float* __restrict__ dinv, unsigned short* __restrict__ out, int n) {
    int gid = blockIdx.x * blockDim.x + threadIdx.x;
    int node = gid >> 4;
    int lane = threadIdx.x & 15;
    if (node >= n) return;
    const short8* f8 = (const short8*)feat;
    float wd = dinv[node];
    short8 a = f8[(size_t)node * 16 + lane];
    float acc[8];
#pragma unroll
    for (int i = 0; i < 8; ++i) acc[i] = bf2f((unsigned short)a[i]) * wd;
    int j = row_start[node], end = row_start[node + 1];
    for (; j + 3 < end; j += 4) {
        int s0 = csr_src[j], s1 = csr_src[j + 1], s2 = csr_src[j + 2], s3 = csr_src[j + 3];
        float w0 = dinv[s0], w1 = dinv[s1], w2 = dinv[s2], w3 = dinv[s3];
        short8 v0 = f8[(size_t)s0 * 16 + lane];
        short8 v1 = f8[(size_t)s1 * 16 + lane];
        short8 v2 = f8[(size_t)s2 * 16 + lane];
        short8 v3 = f8[(size_t)s3 * 16 + lane];
#pragma unroll
        for (int i = 0; i < 8; ++i)
            acc[i] += w0 * bf2f((unsigned short)v0[i]) + w1 * bf2f((unsigned short)v1[i])
                    + w2 * bf2f((unsigned short)v2[i]) + w3 * bf2f((unsigned short)v3[i]);
    }
    for (; j < end; ++j) {
        int s = csr_src[j];
        float w = dinv[s];
        short8 v = f8[(size_t)s * 16 + lane];
#pragma unroll
        for (int i = 0; i < 8; ++i) acc[i] += w * bf2f((unsigned short)v[i]);
    }
    short8 o;
#pragma unroll
    for (int i = 0; i < 8; ++i) o[i] = (short)f2bf(acc[i] * wd);
    ((short8*)out)[(size_t)node * 16 + lane] = o;
}

// ---------------- fused: h1-chunk MFMA (LDS) + pre-partial MFMA ----------------
__global__ __launch_bounds__(512) void k_fused(const unsigned short* __restrict__ agg1,
        const unsigned short* __restrict__ w1t, const float* __restrict__ b1,
        const float* __restrict__ cmT, float* __restrict__ partial) {
    __shared__ unsigned short Ws[256 * 128];  // 64 KB
    __shared__ unsigned short As[64 * 128];   // 16 KB
    __shared__ unsigned short Hs[256 * 64];   // 32 KB
    __shared__ unsigned short Cs[64 * 64];    // 8 KB

    const int tid = threadIdx.x;
    const int sb = blockIdx.x * 512;

#pragma unroll
    for (int i = 0; i < 8; ++i) {
        int c = tid + i * 512;
        int row = c >> 4, seg = c & 15;
        uint4 v = *(const uint4*)(w1t + row * 128 + seg * 8);
        *(uint4*)((char*)Ws + row * 256 + ((seg * 16) ^ ((row & 7) << 4))) = v;
    }

    const int w  = tid >> 6;
    const int l  = tid & 63;
    const int lr = l & 15;
    const int lg = l >> 4;
    const int swz = (lr & 7) << 4;
    const int j0 = w * 32;

    float bb0 = b1[j0 + lr];
    float bb1 = b1[j0 + 16 + lr];

    f32x4 acc2[4][2] = {};

    for (int c = 0; c < 8; ++c) {
        int s0 = sb + c * 64;
        __syncthreads();
#pragma unroll
        for (int i = 0; i < 2; ++i) {
            int cc = tid + i * 512;
            int row = cc >> 4, seg = cc & 15;
            uint4 v = make_uint4(0, 0, 0, 0);
            int node = s0 + row;
            if (node < NN) v = *(const uint4*)(agg1 + (size_t)node * 128 + seg * 8);
            *(uint4*)((char*)As + row * 256 + ((seg * 16) ^ ((row & 7) << 4))) = v;
        }
        {
            int g = tid >> 3, seg = tid & 7;
            const float* cp = cmT + (size_t)g * NNPAD + s0 + seg * 8;
            float4 f0 = *(const float4*)cp;
            float4 f1 = *(const float4*)(cp + 4);
            uint4 v;
            v.x = (unsigned)f2bf(f0.x) | ((unsigned)f2bf(f0.y) << 16);
            v.y = (unsigned)f2bf(f0.z) | ((unsigned)f2bf(f0.w) << 16);
            v.z = (unsigned)f2bf(f1.x) | ((unsigned)f2bf(f1.y) << 16);
            v.w = (unsigned)f2bf(f1.z) | ((unsigned)f2bf(f1.w) << 16);
            *(uint4*)((char*)Cs + g * 128 + ((seg * 16) ^ ((g & 7) << 4))) = v;
        }
        __syncthreads();

        // phase A: h1 chunk = relu(agg1c @ w1t^T + b1), K=128
        f32x4 accA[4][2] = {};
#pragma unroll
        for (int ks = 0; ks < 4; ++ks) {
            int kb = ks * 64 + lg * 16;
            short8 a[4];
#pragma unroll
            for (int m = 0; m < 4; ++m)
                a[m] = *(const short8*)((const char*)As + (m * 16 + lr) * 256 + (kb ^ swz));
#pragma unroll
            for (int n = 0; n < 2; ++n) {
                short8 b = *(const short8*)((const char*)Ws + (j0 + n * 16 + lr) * 256 + (kb ^ swz));
#pragma unroll
                for (int m = 0; m < 4; ++m)
                    accA[m][n] = __builtin_amdgcn_mfma_f32_16x16x32_bf16(a[m], b, accA[m][n], 0, 0, 0);
            }
        }
#pragma unroll
        for (int n = 0; n < 2; ++n) {
            int j = j0 + n * 16 + lr;
            float bbv = n ? bb1 : bb0;
#pragma unroll
            for (int m = 0; m < 4; ++m) {
                float v0 = fmaxf(accA[m][n][0] + bbv, 0.f);
                float v1 = fmaxf(accA[m][n][1] + bbv, 0.f);
                float v2 = fmaxf(accA[m][n][2] + bbv, 0.f);
                float v3 = fmaxf(accA[m][n][3] + bbv, 0.f);
                uint2 p;
                p.x = (unsigned)f2bf(v0) | ((unsigned)f2bf(v1) << 16);
                p.y = (unsigned)f2bf(v2) | ((unsigned)f2bf(v3) << 16);
                *(uint2*)((char*)Hs + j * 128 + (((m * 16 + lg * 4) * 2) ^ swz)) = p;
            }
        }
        __syncthreads();

        // phase B: acc2[g][j] += Cs @ Hs^T, K=64
#pragma unroll
        for (int ks = 0; ks < 2; ++ks) {
            int kb = ks * 64 + lg * 16;
            short8 a[4];
#pragma unroll
            for (int mg = 0; mg < 4; ++mg)
                a[mg] = *(const short8*)((const char*)Cs + (mg * 16 + lr) * 128 + (kb ^ swz));
#pragma unroll
            for (int n = 0; n < 2; ++n) {
                short8 b = *(const short8*)((const char*)Hs + (j0 + n * 16 + lr) * 128 + (kb ^ swz));
#pragma unroll
                for (int mg = 0; mg < 4; ++mg)
                    acc2[mg][n] = __builtin_amdgcn_mfma_f32_16x16x32_bf16(a[mg], b, acc2[mg][n], 0, 0, 0);
            }
        }
    }

    float* pb = partial + (size_t)blockIdx.x * (NG * DH);
#pragma unroll
    for (int mg = 0; mg < 4; ++mg)
#pragma unroll
        for (int n = 0; n < 2; ++n)
#pragma unroll
            for (int r = 0; r < 4; ++r) {
                int g = mg * 16 + lg * 4 + r;
                int j = j0 + n * 16 + lr;
                pb[g * DH + j] = acc2[mg][n][r];
            }
}

// ---------------- tail: reduce 196 partials + final 64x256x128 GEMM ----------------
__global__ __launch_bounds__(256) void k_tail(const float* __restrict__ partial,
        const float* __restrict__ W2, const float* __restrict__ b2,
        const int* __restrict__ cntg, float* __restrict__ out) {
    __shared__ float pre[DH];
    int g = blockIdx.x;
    int t = threadIdx.x;
    float s0 = 0.f, s1 = 0.f, s2 = 0.f, s3 = 0.f;
    for (int b = 0; b < 196; b += 4) {
        s0 += partial[(size_t)b * (NG * DH) + g * DH + t];
        s1 += partial[(size_t)(b + 1) * (NG * DH) + g * DH + t];
        s2 += partial[(size_t)(b + 2) * (NG * DH) + g * DH + t];
        s3 += partial[(size_t)(b + 3) * (NG * DH) + g * DH + t];
    }
    pre[t] = (s0 + s1) + (s2 + s3);
    __syncthreads();
    if (t < DO) {
        float acc = (float)cntg[g] * b2[t];
        for (int k = 0; k < DH; ++k)
            acc = fmaf(pre[k], W2[k * DO + t], acc);
        out[g * DO + t] = acc;
    }
}

// ---------------- launch ----------------

extern "C" void kernel_launch(void* const* d_in, const int* in_sizes, int n_in,
                              void* d_out, int out_size, void* d_ws, size_t ws_size,
                              hipStream_t stream) {
    const float* x     = (const float*)d_in[0];
    const int*   ei    = (const int*)d_in[1];
    const int*   batch = (const int*)d_in[2];
    const float* W1    = (const float*)d_in[3];
    const float* b1    = (const float*)d_in[4];
    const float* W2    = (const float*)d_in[5];
    const float* b2    = (const float*)d_in[6];
    float* out = (float*)d_out;

    const int* src = ei;
    const int* dst = ei + NE;

    // workspace layout, peak ~98.6 MB
    char* ws = (char*)d_ws;
    float*          dinv    = (float*)(ws + 0);                  // 400 KB
    int*            cnt_in  = (int*)(ws + 524288);               // deg -> cursor
    int*            rowst   = (int*)(ws + 1048576);              // NN+1
    int*            bsum    = (int*)(ws + 1572864);
    int*            cntg    = (int*)(ws + 1576960);
    unsigned short* w1t     = (unsigned short*)(ws + 1577216);   // 64 KB
    int2*           gdv     = (int2*)(ws + 1642752);             // 800 KB
    int*            csr     = (int*)(ws + 2443264);              // 6.4 MB
    unsigned short* xbf     = (unsigned short*)(ws + 8843264);   // 25.6 MB
    unsigned short* agg1    = (unsigned short*)(ws + 34443264);  // 25.6 MB
    float*          cmT     = (float*)(ws + 60043264);           // 25.69 MB
    float*          partial = (float*)(ws + 85733376);           // 12.85 MB

    const int BLK = 256;
    auto cdiv = [](int a, int b) { return (a + b - 1) / b; };
    const int NB = cdiv(NN, 256);   // 391

    // ---- async zero-init (cursor/deg only; cmT is fully overwritten) ----
    hipMemsetAsync(cnt_in, 0, (size_t)NN * 4, stream);

    // ---- prep (cvt + wt) merged with dst histogram ----
    k_prep<<<cdiv(NN * 32 + DI * DH, BLK), BLK, 0, stream>>>(x, xbf, W1, w1t, dst, cnt_in);

    // ---- scan (+ dinv/gdv/graph-counts) ----
    k_scan1<<<NB, 256, 0, stream>>>(cnt_in, rowst, bsum, NN);
    k_scan2<<<1, 512, 0, stream>>>(bsum, cntg, NB);
    k_scan3<<<NB, 256, 0, stream>>>(rowst, bsum, cnt_in, dinv, batch, gdv, cntg, NN, NE);

    // ---- CSR fill (4 dst-range passes) ----
    {
        const int NPASS = 4, NPP = (NN + NPASS - 1) / NPASS;
        for (int p = 0; p < NPASS; ++p)
            k_fill_csr<<<cdiv(NE, BLK), BLK, 0, stream>>>(src, dst, cnt_in, csr, NE,
                                                          p * NPP, (p + 1) * NPP);
    }

    // ---- cmT from CSR (LDS-accumulated, coalesced stores) ----
    k_cmbuild<<<NG * 4, 256, 0, stream>>>(csr, rowst, dinv, gdv, batch, cmT);

    // ---- layer 1 aggregation ----
    k_agg16<<<cdiv(NN * 16, BLK), BLK, 0, stream>>>(xbf, csr, rowst, dinv, agg1, NN);

    // ---- fused h1 + pre-partials (MFMA) ----
    k_fused<<<NNPAD / 512, 512, 0, stream>>>(agg1, w1t, b1, cmT, partial);

    // ---- tail ----
    k_tail<<<NG, 256, 0, stream>>>(partial, W2, b2, cntg, out);
}

// Round 13
// 345.621 us; speedup vs baseline: 1.0861x; 1.0861x over previous
//
#include <hip/hip_runtime.h>

#define NN 100000
#define NNPAD 100352   // 196*512 = 8*12544
#define NE 1600000
#define NG 64
#define DI 128
#define DH 256
#define DO 128
#define SEG2 25088     // cmT s-segment per block (~100 KB LDS), NNPAD = 4*SEG2

using short8 = __attribute__((ext_vector_type(8))) short;
using f32x4  = __attribute__((ext_vector_type(4))) float;

__device__ __forceinline__ float bf2f(unsigned short u) {
    return __uint_as_float(((unsigned)u) << 16);
}
__device__ __forceinline__ unsigned short f2bf(float f) {
    unsigned u = __float_as_uint(f);
    unsigned r = (u + 0x7FFFu + ((u >> 16) & 1u)) >> 16;   // RNE
    return (unsigned short)r;
}

// ---------------- prep: x -> bf16, W1 -> w1t, dst histogram (merged) ----------------
__global__ void k_prep(const float* __restrict__ x, unsigned short* __restrict__ xbf,
                       const float* __restrict__ W1, unsigned short* __restrict__ w1t,
                       const int* __restrict__ dst, int* __restrict__ cnt) {
    int i = blockIdx.x * blockDim.x + threadIdx.x;
    const int NX4 = NN * 32;
    if (i < NX4) {
        float4 v = ((const float4*)x)[i];
        ushort4 o;
        o.x = f2bf(v.x); o.y = f2bf(v.y); o.z = f2bf(v.z); o.w = f2bf(v.w);
        ((ushort4*)xbf)[i] = o;
    } else if (i < NX4 + DI * DH) {
        int t = i - NX4;
        int k = t / DH, n = t % DH;
        w1t[n * DI + k] = f2bf(W1[t]);
    }
    if (i < NE) atomicAdd(&cnt[dst[i]], 1);
}

// ---------------- exclusive scan (2-level) ----------------

__global__ void k_scan1(const int* __restrict__ in, int* __restrict__ out,
                        int* __restrict__ bsum, int n) {
    __shared__ int sh[256];
    int t = threadIdx.x;
    int i = blockIdx.x * 256 + t;
    int v = (i < n) ? in[i] : 0;
    sh[t] = v;
    __syncthreads();
    for (int off = 1; off < 256; off <<= 1) {
        int add = (t >= off) ? sh[t - off] : 0;
        __syncthreads();
        sh[t] += add;
        __syncthreads();
    }
    if (i < n) out[i] = sh[t] - v;
    if (t == 255) bsum[blockIdx.x] = sh[255];
}
__global__ void k_scan2(int* __restrict__ bsum, int* __restrict__ cntg, int nb) {
    __shared__ int sh[512];
    int t = threadIdx.x;
    if (t < NG) cntg[t] = 0;
    int v = (t < nb) ? bsum[t] : 0;
    sh[t] = v;
    __syncthreads();
    for (int off = 1; off < 512; off <<= 1) {
        int add = (t >= off) ? sh[t - off] : 0;
        __syncthreads();
        sh[t] += add;
        __syncthreads();
    }
    if (t < nb) bsum[t] = sh[t] - v;
}
// finalize rowst/cursor, dinv, gdv, per-graph counts
__global__ void k_scan3(int* __restrict__ rowst, const int* __restrict__ bsum,
                        int* __restrict__ cursor_deg, float* __restrict__ dinv,
                        const int* __restrict__ batch, int2* __restrict__ gdv,
                        int* __restrict__ cntg, int n, int total) {
    __shared__ int sh[NG];
    int t = threadIdx.x;
    if (t < NG) sh[t] = 0;
    __syncthreads();
    int i = blockIdx.x * 256 + t;
    if (i < n) {
        int deg = cursor_deg[i];
        float dv = rsqrtf((float)(deg + 1));
        dinv[i] = dv;
        int b = batch[i];
        int2 g; g.x = __float_as_int(dv); g.y = b;
        gdv[i] = g;
        atomicAdd(&sh[b], 1);
        int rv = rowst[i] + bsum[blockIdx.x];
        rowst[i] = rv;
        cursor_deg[i] = rv;   // becomes fill cursor
    }
    if (i == 0) rowst[n] = total;
    __syncthreads();
    if (t < NG && sh[t]) atomicAdd(&cntg[t], sh[t]);
}

// ---------------- CSR fill: dst-range passes, packed (src, weight) ----------------

__global__ void k_fill_csr(const int* __restrict__ src, const int* __restrict__ dst,
                           const int2* __restrict__ gdv, const float* __restrict__ dinv,
                           int* __restrict__ cursor, int2* __restrict__ csr8,
                           int e, int lo, int hi) {
    int i = blockIdx.x * blockDim.x + threadIdx.x;
    if (i < e) {
        int d = dst[i];
        if (d >= lo && d < hi) {
            int s = src[i];
            float w = dinv[s] * __int_as_float(gdv[d].x);
            int pos = atomicAdd(&cursor[d], 1);
            csr8[pos] = make_int2(s, __float_as_int(w));
        }
    }
}

// ---------------- cmT build: flat streaming over per-graph contiguous (s,w) pairs ----------------
// Block (g, seg): LDS-accumulate cmT[g][slo..slo+SEG2) over graph g's edge range,
// add self-loop diagonal, store coalesced.
__global__ __launch_bounds__(256) void k_cmbuild(const int2* __restrict__ csr8,
        const int* __restrict__ rowst, const int* __restrict__ batch,
        const int2* __restrict__ gdv, float* __restrict__ cmT) {
    __shared__ float acc[SEG2];          // ~100 KB
    int g   = blockIdx.x >> 2;
    int seg = blockIdx.x & 3;
    int slo = seg * SEG2;
    int t = threadIdx.x;
    for (int i = t; i < SEG2; i += 256) acc[i] = 0.f;

    // graph g's dst range via binary search on sorted batch
    int lo = 0, hi = NN;
    while (lo < hi) { int m = (lo + hi) >> 1; if (batch[m] < g) lo = m + 1; else hi = m; }
    int dstart = lo;
    int lo2 = lo, hi2 = NN;
    while (lo2 < hi2) { int m = (lo2 + hi2) >> 1; if (batch[m] < g + 1) lo2 = m + 1; else hi2 = m; }
    int e0 = rowst[dstart], e1 = rowst[lo2];
    __syncthreads();

    int j = e0 + t;
    for (; j + 768 < e1; j += 1024) {
        int2 p0 = csr8[j];
        int2 p1 = csr8[j + 256];
        int2 p2 = csr8[j + 512];
        int2 p3 = csr8[j + 768];
        int a0 = p0.x - slo, a1 = p1.x - slo, a2 = p2.x - slo, a3 = p3.x - slo;
        if ((unsigned)a0 < SEG2) atomicAdd(&acc[a0], __int_as_float(p0.y));
        if ((unsigned)a1 < SEG2) atomicAdd(&acc[a1], __int_as_float(p1.y));
        if ((unsigned)a2 < SEG2) atomicAdd(&acc[a2], __int_as_float(p2.y));
        if ((unsigned)a3 < SEG2) atomicAdd(&acc[a3], __int_as_float(p3.y));
    }
    for (; j < e1; j += 256) {
        int2 p = csr8[j];
        int a = p.x - slo;
        if ((unsigned)a < SEG2) atomicAdd(&acc[a], __int_as_float(p.y));
    }
    __syncthreads();

    float* row = cmT + (size_t)g * NNPAD;
    for (int i = t; i < SEG2; i += 256) {
        int s = slo + i;
        float v = acc[i];
        if (s < NN) {
            int2 gv = gdv[s];
            if (gv.y == g) { float dv = __int_as_float(gv.x); v += dv * dv; }
        }
        row[s] = v;
    }
}

// ---------------- layer-1 aggregation: weights streamed from packed CSR ----------------
__global__ __launch_bounds__(256) void k_agg16(const unsigned short* __restrict__ feat,
        const int2* __restrict__ csr8, const int* __restrict__ row_start,
        const float* __restrict__ dinv, unsigned short* __restrict__ out, int n) {
    int gid = blockIdx.x * blockDim.x + threadIdx.x;
    int node = gid >> 4;
    int lane = threadIdx.x & 15;
    if (node >= n) return;
    const short8* f8 = (const short8*)feat;
    float wd = dinv[node];
    float wd2 = wd * wd;
    short8 a = f8[(size_t)node * 16 + lane];
    float acc[8];
#pragma unroll
    for (int i = 0; i < 8; ++i) acc[i] = bf2f((unsigned short)a[i]) * wd2;
    int j = row_start[node], end = row_start[node + 1];
    for (; j + 3 < end; j += 4) {
        int2 p0 = csr8[j], p1 = csr8[j + 1], p2 = csr8[j + 2], p3 = csr8[j + 3];
        float w0 = __int_as_float(p0.y), w1 = __int_as_float(p1.y);
        float w2 = __int_as_float(p2.y), w3 = __int_as_float(p3.y);
        short8 v0 = f8[(size_t)p0.x * 16 + lane];
        short8 v1 = f8[(size_t)p1.x * 16 + lane];
        short8 v2 = f8[(size_t)p2.x * 16 + lane];
        short8 v3 = f8[(size_t)p3.x * 16 + lane];
#pragma unroll
        for (int i = 0; i < 8; ++i)
            acc[i] += w0 * bf2f((unsigned short)v0[i]) + w1 * bf2f((unsigned short)v1[i])
                    + w2 * bf2f((unsigned short)v2[i]) + w3 * bf2f((unsigned short)v3[i]);
    }
    for (; j < end; ++j) {
        int2 p = csr8[j];
        float w = __int_as_float(p.y);
        short8 v = f8[(size_t)p.x * 16 + lane];
#pragma unroll
        for (int i = 0; i < 8; ++i) acc[i] += w * bf2f((unsigned short)v[i]);
    }
    short8 o;
#pragma unroll
    for (int i = 0; i < 8; ++i) o[i] = (short)f2bf(acc[i]);
    ((short8*)out)[(size_t)node * 16 + lane] = o;
}

// ---------------- fused: h1-chunk MFMA (LDS) + pre-partial MFMA ----------------
__global__ __launch_bounds__(512) void k_fused(const unsigned short* __restrict__ agg1,
        const unsigned short* __restrict__ w1t, const float* __restrict__ b1,
        const float* __restrict__ cmT, float* __restrict__ partial) {
    __shared__ unsigned short Ws[256 * 128];  // 64 KB
    __shared__ unsigned short As[64 * 128];   // 16 KB
    __shared__ unsigned short Hs[256 * 64];   // 32 KB
    __shared__ unsigned short Cs[64 * 64];    // 8 KB

    const int tid = threadIdx.x;
    const int sb = blockIdx.x * 512;

#pragma unroll
    for (int i = 0; i < 8; ++i) {
        int c = tid + i * 512;
        int row = c >> 4, seg = c & 15;
        uint4 v = *(const uint4*)(w1t + row * 128 + seg * 8);
        *(uint4*)((char*)Ws + row * 256 + ((seg * 16) ^ ((row & 7) << 4))) = v;
    }

    const int w  = tid >> 6;
    const int l  = tid & 63;
    const int lr = l & 15;
    const int lg = l >> 4;
    const int swz = (lr & 7) << 4;
    const int j0 = w * 32;

    float bb0 = b1[j0 + lr];
    float bb1 = b1[j0 + 16 + lr];

    f32x4 acc2[4][2] = {};

    for (int c = 0; c < 8; ++c) {
        int s0 = sb + c * 64;
        __syncthreads();
#pragma unroll
        for (int i = 0; i < 2; ++i) {
            int cc = tid + i * 512;
            int row = cc >> 4, seg = cc & 15;
            uint4 v = make_uint4(0, 0, 0, 0);
            int node = s0 + row;
            if (node < NN) v = *(const uint4*)(agg1 + (size_t)node * 128 + seg * 8);
            *(uint4*)((char*)As + row * 256 + ((seg * 16) ^ ((row & 7) << 4))) = v;
        }
        {
            int g = tid >> 3, seg = tid & 7;
            const float* cp = cmT + (size_t)g * NNPAD + s0 + seg * 8;
            float4 f0 = *(const float4*)cp;
            float4 f1 = *(const float4*)(cp + 4);
            uint4 v;
            v.x = (unsigned)f2bf(f0.x) | ((unsigned)f2bf(f0.y) << 16);
            v.y = (unsigned)f2bf(f0.z) | ((unsigned)f2bf(f0.w) << 16);
            v.z = (unsigned)f2bf(f1.x) | ((unsigned)f2bf(f1.y) << 16);
            v.w = (unsigned)f2bf(f1.z) | ((unsigned)f2bf(f1.w) << 16);
            *(uint4*)((char*)Cs + g * 128 + ((seg * 16) ^ ((g & 7) << 4))) = v;
        }
        __syncthreads();

        // phase A: h1 chunk = relu(agg1c @ w1t^T + b1), K=128
        f32x4 accA[4][2] = {};
#pragma unroll
        for (int ks = 0; ks < 4; ++ks) {
            int kb = ks * 64 + lg * 16;
            short8 a[4];
#pragma unroll
            for (int m = 0; m < 4; ++m)
                a[m] = *(const short8*)((const char*)As + (m * 16 + lr) * 256 + (kb ^ swz));
#pragma unroll
            for (int n = 0; n < 2; ++n) {
                short8 b = *(const short8*)((const char*)Ws + (j0 + n * 16 + lr) * 256 + (kb ^ swz));
#pragma unroll
                for (int m = 0; m < 4; ++m)
                    accA[m][n] = __builtin_amdgcn_mfma_f32_16x16x32_bf16(a[m], b, accA[m][n], 0, 0, 0);
            }
        }
#pragma unroll
        for (int n = 0; n < 2; ++n) {
            int j = j0 + n * 16 + lr;
            float bbv = n ? bb1 : bb0;
#pragma unroll
            for (int m = 0; m < 4; ++m) {
                float v0 = fmaxf(accA[m][n][0] + bbv, 0.f);
                float v1 = fmaxf(accA[m][n][1] + bbv, 0.f);
                float v2 = fmaxf(accA[m][n][2] + bbv, 0.f);
                float v3 = fmaxf(accA[m][n][3] + bbv, 0.f);
                uint2 p;
                p.x = (unsigned)f2bf(v0) | ((unsigned)f2bf(v1) << 16);
                p.y = (unsigned)f2bf(v2) | ((unsigned)f2bf(v3) << 16);
                *(uint2*)((char*)Hs + j * 128 + (((m * 16 + lg * 4) * 2) ^ swz)) = p;
            }
        }
        __syncthreads();

        // phase B: acc2[g][j] += Cs @ Hs^T, K=64
#pragma unroll
        for (int ks = 0; ks < 2; ++ks) {
            int kb = ks * 64 + lg * 16;
            short8 a[4];
#pragma unroll
            for (int mg = 0; mg < 4; ++mg)
                a[mg] = *(const short8*)((const char*)Cs + (mg * 16 + lr) * 128 + (kb ^ swz));
#pragma unroll
            for (int n = 0; n < 2; ++n) {
                short8 b = *(const short8*)((const char*)Hs + (j0 + n * 16 + lr) * 128 + (kb ^ swz));
#pragma unroll
                for (int mg = 0; mg < 4; ++mg)
                    acc2[mg][n] = __builtin_amdgcn_mfma_f32_16x16x32_bf16(a[mg], b, acc2[mg][n], 0, 0, 0);
            }
        }
    }

    float* pb = partial + (size_t)blockIdx.x * (NG * DH);
#pragma unroll
    for (int mg = 0; mg < 4; ++mg)
#pragma unroll
        for (int n = 0; n < 2; ++n)
#pragma unroll
            for (int r = 0; r < 4; ++r) {
                int g = mg * 16 + lg * 4 + r;
                int j = j0 + n * 16 + lr;
                pb[g * DH + j] = acc2[mg][n][r];
            }
}

// ---------------- tail: reduce 196 partials + final 64x256x128 GEMM ----------------
__global__ __launch_bounds__(256) void k_tail(const float* __restrict__ partial,
        const float* __restrict__ W2, const float* __restrict__ b2,
        const int* __restrict__ cntg, float* __restrict__ out) {
    __shared__ float pre[DH];
    int g = blockIdx.x;
    int t = threadIdx.x;
    float s0 = 0.f, s1 = 0.f, s2 = 0.f, s3 = 0.f;
    for (int b = 0; b < 196; b += 4) {
        s0 += partial[(size_t)b * (NG * DH) + g * DH + t];
        s1 += partial[(size_t)(b + 1) * (NG * DH) + g * DH + t];
        s2 += partial[(size_t)(b + 2) * (NG * DH) + g * DH + t];
        s3 += partial[(size_t)(b + 3) * (NG * DH) + g * DH + t];
    }
    pre[t] = (s0 + s1) + (s2 + s3);
    __syncthreads();
    if (t < DO) {
        float acc = (float)cntg[g] * b2[t];
        for (int k = 0; k < DH; ++k)
            acc = fmaf(pre[k], W2[k * DO + t], acc);
        out[g * DO + t] = acc;
    }
}

// ---------------- launch ----------------

extern "C" void kernel_launch(void* const* d_in, const int* in_sizes, int n_in,
                              void* d_out, int out_size, void* d_ws, size_t ws_size,
                              hipStream_t stream) {
    const float* x     = (const float*)d_in[0];
    const int*   ei    = (const int*)d_in[1];
    const int*   batch = (const int*)d_in[2];
    const float* W1    = (const float*)d_in[3];
    const float* b1    = (const float*)d_in[4];
    const float* W2    = (const float*)d_in[5];
    const float* b2    = (const float*)d_in[6];
    float* out = (float*)d_out;

    const int* src = ei;
    const int* dst = ei + NE;

    // workspace layout, peak ~105 MB
    char* ws = (char*)d_ws;
    float*          dinv    = (float*)(ws + 0);                  // 400 KB
    int*            cnt_in  = (int*)(ws + 524288);               // deg -> cursor
    int*            rowst   = (int*)(ws + 1048576);              // NN+1
    int*            bsum    = (int*)(ws + 1572864);
    int*            cntg    = (int*)(ws + 1576960);
    unsigned short* w1t     = (unsigned short*)(ws + 1577216);   // 64 KB
    int2*           gdv     = (int2*)(ws + 1642752);             // 800 KB
    int2*           csr8    = (int2*)(ws + 2443264);             // 12.8 MB
    unsigned short* xbf     = (unsigned short*)(ws + 15243264);  // 25.6 MB
    unsigned short* agg1    = (unsigned short*)(ws + 40843264);  // 25.6 MB
    float*          cmT     = (float*)(ws + 66443264);           // 25.69 MB
    float*          partial = (float*)(ws + 92133376);           // 12.85 MB

    const int BLK = 256;
    auto cdiv = [](int a, int b) { return (a + b - 1) / b; };
    const int NB = cdiv(NN, 256);   // 391

    // ---- async zero-init (cursor/deg only) ----
    hipMemsetAsync(cnt_in, 0, (size_t)NN * 4, stream);

    // ---- prep (cvt + wt + dst histogram) ----
    k_prep<<<cdiv(NN * 32 + DI * DH, BLK), BLK, 0, stream>>>(x, xbf, W1, w1t, dst, cnt_in);

    // ---- scan (+ dinv/gdv/graph-counts) ----
    k_scan1<<<NB, 256, 0, stream>>>(cnt_in, rowst, bsum, NN);
    k_scan2<<<1, 512, 0, stream>>>(bsum, cntg, NB);
    k_scan3<<<NB, 256, 0, stream>>>(rowst, bsum, cnt_in, dinv, batch, gdv, cntg, NN, NE);

    // ---- CSR fill: 4 dst-range passes, packed (s, w) ----
    {
        const int NPASS = 4, NPP = (NN + NPASS - 1) / NPASS;
        for (int p = 0; p < NPASS; ++p)
            k_fill_csr<<<cdiv(NE, BLK), BLK, 0, stream>>>(src, dst, gdv, dinv, cnt_in, csr8,
                                                          NE, p * NPP, (p + 1) * NPP);
    }

    // ---- cmT from packed CSR (flat streaming, LDS-accumulated) ----
    k_cmbuild<<<NG * 4, 256, 0, stream>>>(csr8, rowst, batch, gdv, cmT);

    // ---- layer 1 aggregation ----
    k_agg16<<<cdiv(NN * 16, BLK), BLK, 0, stream>>>(xbf, csr8, rowst, dinv, agg1, NN);

    // ---- fused h1 + pre-partials (MFMA) ----
    k_fused<<<NNPAD / 512, 512, 0, stream>>>(agg1, w1t, b1, cmT, partial);

    // ---- tail ----
    k_tail<<<NG, 256, 0, stream>>>(partial, W2, b2, cntg, out);
}